// Round 1
// baseline (1615.435 us; speedup 1.0000x reference)
//
#include <hip/hip_runtime.h>
#include <hip/hip_bf16.h>
#include <stdint.h>

typedef __attribute__((ext_vector_type(8))) short short8;
typedef __attribute__((ext_vector_type(4))) float f32x4;
typedef unsigned short u16;

#define E_N 1000000
#define T_N 2000000

// workspace layout (bytes)
#define OFF_PSUM 0ULL                      // 1e6 * 64 * 4 = 256,000,000
#define OFF_CNT  256000000ULL              // 1e6 * 4    =   4,000,000
#define OFF_EBF  260000000ULL              // 1e6 * 64 * 2 = 128,000,000
#define OFF_WP1  388000000ULL              // 20*128*8*2 = 40,960
#define OFF_WP2  (OFF_WP1 + 40960ULL)      // 16*128*8*2 = 32,768
#define OFF_WP3  (OFF_WP2 + 32768ULL)      // 16*64*8*2  = 16,384

// LDS layout for k_triplet (bytes)
#define LDS_XHM   0        // 128*160*2 = 40960 (X), later H/M as [128][128] swizzled
#define LDS_W1    40960    // 40960
#define LDS_W2    81920    // 32768
#define LDS_W3    114688   // 16384
#define LDS_EIJ   131072   // 128*4
#define LDS_EKJ   131584   // 128*4
#define LDS_TOTAL 132096

__device__ __forceinline__ u16 f2bf(float f) {
  union { float f; uint32_t u; } c; c.f = f;
  uint32_t u = c.u;
  return (u16)((u + 0x7FFFu + ((u >> 16) & 1u)) >> 16);  // RNE
}
__device__ __forceinline__ float bf2f(u16 h) {
  union { uint32_t u; float f; } c; c.u = ((uint32_t)h) << 16;
  return c.f;
}
__device__ __forceinline__ float silu(float y) {
  return y / (1.0f + __expf(-y));
}

#define MFMA16(a, b, c) __builtin_amdgcn_mfma_f32_16x16x32_bf16((a), (b), (c), 0, 0, 0)

// ---------------- prep kernels ----------------

__global__ __launch_bounds__(256) void k_conv_edge(const float* __restrict__ ef,
                                                   u16* __restrict__ ebf) {
  int i = blockIdx.x * 256 + threadIdx.x;      // i < 16,000,000 (E*64/4)
  float4 v = ((const float4*)ef)[i];
  ushort4 o;
  o.x = f2bf(v.x); o.y = f2bf(v.y); o.z = f2bf(v.z); o.w = f2bf(v.w);
  ((ushort4*)ebf)[i] = o;
}

// pack weights bf16 into B-fragment order: wp[(k>>3)*N + n][k&7]
__global__ __launch_bounds__(256) void k_pack_w(const float* __restrict__ W1,
                                                const float* __restrict__ W2,
                                                const float* __restrict__ W3,
                                                u16* __restrict__ wp1,
                                                u16* __restrict__ wp2,
                                                u16* __restrict__ wp3) {
  int i = blockIdx.x * 256 + threadIdx.x;      // < 45056
  if (i < 20480) {                             // W1: K padded 132->160, N=128
    int j = i & 7, n = (i >> 3) & 127, kb = i >> 10;
    int k = kb * 8 + j;
    wp1[i] = (k < 132) ? f2bf(W1[k * 128 + n]) : (u16)0;
  } else if (i < 36864) {                      // W2: K=128, N=128
    int i2 = i - 20480;
    int j = i2 & 7, n = (i2 >> 3) & 127, kb = i2 >> 10;
    wp2[i2] = f2bf(W2[(kb * 8 + j) * 128 + n]);
  } else if (i < 45056) {                      // W3: K=128, N=64
    int i3 = i - 36864;
    int j = i3 & 7, n = (i3 >> 3) & 63, kb = i3 >> 9;
    wp3[i3] = f2bf(W3[(kb * 8 + j) * 64 + n]);
  }
}

// ---------------- main triplet kernel ----------------
// tile = 128 triplets, 512 threads = 8 waves, waves as 2(M) x 4(N)
// GEMM1: [128x160]x[160x128]  GEMM2: [128x128]x[128x128]  GEMM3: [128x128]x[128x64]

__device__ __forceinline__ void ln_pass(char* smem, int tid,
                                        const float* __restrict__ gamma,
                                        const float* __restrict__ beta) {
  // region: [128 rows][128 cols] bf16, row stride 256B, byte ^= (row&7)<<4 swizzle
  int r = tid >> 2, s = tid & 3;
  int swz = (r & 7) << 4;
  float v[32];
#pragma unroll
  for (int i = 0; i < 4; ++i) {
    short8 h = *(const short8*)(smem + r * 256 + ((s * 64 + i * 16) ^ swz));
#pragma unroll
    for (int j = 0; j < 8; ++j) v[i * 8 + j] = bf2f((u16)h[j]);
  }
  float sum = 0.f, ss = 0.f;
#pragma unroll
  for (int i = 0; i < 32; ++i) { sum += v[i]; ss += v[i] * v[i]; }
  sum += __shfl_xor(sum, 1); ss += __shfl_xor(ss, 1);
  sum += __shfl_xor(sum, 2); ss += __shfl_xor(ss, 2);
  float mu = sum * (1.0f / 128.0f);
  float inv = rsqrtf(ss * (1.0f / 128.0f) - mu * mu + 1e-5f);
#pragma unroll
  for (int i = 0; i < 4; ++i) {
    const float4* gp = (const float4*)(gamma + s * 32 + i * 8);
    const float4* bp = (const float4*)(beta + s * 32 + i * 8);
    float4 ga = gp[0], gb = gp[1], ba = bp[0], bb = bp[1];
    float gg[8] = {ga.x, ga.y, ga.z, ga.w, gb.x, gb.y, gb.z, gb.w};
    float be[8] = {ba.x, ba.y, ba.z, ba.w, bb.x, bb.y, bb.z, bb.w};
    short8 o;
#pragma unroll
    for (int j = 0; j < 8; ++j) {
      float nv = (v[i * 8 + j] - mu) * inv * gg[j] + be[j];
      o[j] = (short)f2bf(nv);
    }
    *(short8*)(smem + r * 256 + ((s * 64 + i * 16) ^ swz)) = o;
  }
}

__global__ __launch_bounds__(512, 2) void k_triplet(
    const u16* __restrict__ ebf, const int* __restrict__ tidx,
    const float* __restrict__ geo,
    const u16* __restrict__ wp1, const u16* __restrict__ wp2, const u16* __restrict__ wp3,
    const float* __restrict__ b1, const float* __restrict__ g1, const float* __restrict__ be1,
    const float* __restrict__ b2, const float* __restrict__ g2, const float* __restrict__ be2,
    float* __restrict__ psum, float* __restrict__ cnt) {
  extern __shared__ char smem[];
  char* W1s = smem + LDS_W1;
  char* W2s = smem + LDS_W2;
  char* W3s = smem + LDS_W3;
  int* EIJ = (int*)(smem + LDS_EIJ);
  int* EKJ = (int*)(smem + LDS_EKJ);

  const int tid = threadIdx.x;
  const int wave = tid >> 6, lane = tid & 63;
  const int wm = wave >> 2, wn = wave & 3;   // 2 x 4
  const int l15 = lane & 15, lg = lane >> 4;
  const int t0 = blockIdx.x * 128;

  // stage packed weights (linear copies)
  {
    uint4* d1 = (uint4*)W1s; const uint4* s1 = (const uint4*)wp1;
    for (int i = tid; i < 2560; i += 512) d1[i] = s1[i];
    uint4* d2 = (uint4*)W2s; const uint4* s2 = (const uint4*)wp2;
    for (int i = tid; i < 2048; i += 512) d2[i] = s2[i];
    uint4* d3 = (uint4*)W3s; const uint4* s3 = (const uint4*)wp3;
    for (int i = tid; i < 1024; i += 512) d3[i] = s3[i];
  }
  if (tid < 128) {
    int2 p = ((const int2*)tidx)[t0 + tid];
    EIJ[tid] = p.x; EKJ[tid] = p.y;
    atomicAdd(&cnt[p.x], 1.0f);
  }
  __syncthreads();

  // stage X = [f_ij | f_kj | geo | 0pad] as [128][160] bf16, row stride 320B
  {
    const int r = tid >> 2, s = tid & 3;
    const int e = (s < 2) ? EIJ[r] : EKJ[r];
    const uint4* src = (const uint4*)(ebf + (size_t)e * 64) + (s & 1) * 4;
    uint4* dst = (uint4*)smem + (r * 20 + s * 4);
    uint4 v0 = src[0], v1 = src[1], v2 = src[2], v3 = src[3];
    dst[0] = v0; dst[1] = v1; dst[2] = v2; dst[3] = v3;
    if (s == 0) {
      float4 gq = ((const float4*)geo)[t0 + r];
      ushort4 gb;
      gb.x = f2bf(gq.x); gb.y = f2bf(gq.y); gb.z = f2bf(gq.z); gb.w = f2bf(gq.w);
      *(ushort4*)(smem + r * 320 + 256) = gb;          // halves 128..131
      uint2 z; z.x = 0; z.y = 0;
      *(uint2*)(smem + r * 320 + 264) = z;             // halves 132..135
    } else {
      uint4 z; z.x = 0; z.y = 0; z.z = 0; z.w = 0;
      *(uint4*)(smem + r * 320 + 256 + s * 16) = z;    // halves 136..159
    }
  }
  __syncthreads();

  f32x4 acc[4][2];
#pragma unroll
  for (int mf = 0; mf < 4; ++mf)
#pragma unroll
    for (int f = 0; f < 2; ++f) acc[mf][f] = (f32x4)0.0f;

  // ---- GEMM1: X @ W1, K=160 ----
#pragma unroll
  for (int s5 = 0; s5 < 5; ++s5) {
    short8 a[4], bfr[2];
#pragma unroll
    for (int mf = 0; mf < 4; ++mf) {
      int row = wm * 64 + mf * 16 + l15;
      a[mf] = *(const short8*)(smem + row * 320 + s5 * 64 + lg * 16);
    }
#pragma unroll
    for (int f = 0; f < 2; ++f) {
      int n = wn * 32 + f * 16 + l15;
      int kblk = s5 * 4 + lg;
      bfr[f] = *(const short8*)(W1s + ((kblk * 128 + n) << 4));
    }
#pragma unroll
    for (int mf = 0; mf < 4; ++mf)
#pragma unroll
      for (int f = 0; f < 2; ++f) acc[mf][f] = MFMA16(a[mf], bfr[f], acc[mf][f]);
  }
  {
    float bias[2] = {b1[wn * 32 + l15], b1[wn * 32 + 16 + l15]};
    __syncthreads();  // everyone done reading X
#pragma unroll
    for (int mf = 0; mf < 4; ++mf)
#pragma unroll
      for (int f = 0; f < 2; ++f)
#pragma unroll
        for (int q = 0; q < 4; ++q) {
          float sil = silu(acc[mf][f][q] + bias[f]);
          int row = wm * 64 + mf * 16 + lg * 4 + q;
          int colb = (wn * 32 + f * 16 + l15) << 1;
          *(u16*)(smem + row * 256 + (colb ^ ((row & 7) << 4))) = f2bf(sil);
        }
  }
  __syncthreads();
  ln_pass(smem, tid, g1, be1);
  __syncthreads();

  // ---- GEMM2: H @ W2, K=128 ----
#pragma unroll
  for (int mf = 0; mf < 4; ++mf)
#pragma unroll
    for (int f = 0; f < 2; ++f) acc[mf][f] = (f32x4)0.0f;
#pragma unroll
  for (int s4 = 0; s4 < 4; ++s4) {
    short8 a[4], bfr[2];
#pragma unroll
    for (int mf = 0; mf < 4; ++mf) {
      int row = wm * 64 + mf * 16 + l15;
      a[mf] = *(const short8*)(smem + row * 256 + ((s4 * 64 + lg * 16) ^ ((row & 7) << 4)));
    }
#pragma unroll
    for (int f = 0; f < 2; ++f) {
      int n = wn * 32 + f * 16 + l15;
      int kblk = s4 * 4 + lg;
      bfr[f] = *(const short8*)(W2s + ((kblk * 128 + n) << 4));
    }
#pragma unroll
    for (int mf = 0; mf < 4; ++mf)
#pragma unroll
      for (int f = 0; f < 2; ++f) acc[mf][f] = MFMA16(a[mf], bfr[f], acc[mf][f]);
  }
  {
    float bias[2] = {b2[wn * 32 + l15], b2[wn * 32 + 16 + l15]};
    __syncthreads();  // everyone done reading H
#pragma unroll
    for (int mf = 0; mf < 4; ++mf)
#pragma unroll
      for (int f = 0; f < 2; ++f)
#pragma unroll
        for (int q = 0; q < 4; ++q) {
          float sil = silu(acc[mf][f][q] + bias[f]);
          int row = wm * 64 + mf * 16 + lg * 4 + q;
          int colb = (wn * 32 + f * 16 + l15) << 1;
          *(u16*)(smem + row * 256 + (colb ^ ((row & 7) << 4))) = f2bf(sil);
        }
  }
  __syncthreads();
  ln_pass(smem, tid, g2, be2);
  __syncthreads();

  // ---- GEMM3: M @ W3, K=128, N=64; atomic scatter into psum ----
  f32x4 acc3[4];
#pragma unroll
  for (int mf = 0; mf < 4; ++mf) acc3[mf] = (f32x4)0.0f;
#pragma unroll
  for (int s4 = 0; s4 < 4; ++s4) {
    short8 a[4];
#pragma unroll
    for (int mf = 0; mf < 4; ++mf) {
      int row = wm * 64 + mf * 16 + l15;
      a[mf] = *(const short8*)(smem + row * 256 + ((s4 * 64 + lg * 16) ^ ((row & 7) << 4)));
    }
    int n = wn * 16 + l15;
    int kblk = s4 * 4 + lg;
    short8 bfr = *(const short8*)(W3s + ((kblk * 64 + n) << 4));
#pragma unroll
    for (int mf = 0; mf < 4; ++mf) acc3[mf] = MFMA16(a[mf], bfr, acc3[mf]);
  }
  {
    int col = wn * 16 + l15;
#pragma unroll
    for (int mf = 0; mf < 4; ++mf)
#pragma unroll
      for (int q = 0; q < 4; ++q) {
        int row = wm * 64 + mf * 16 + lg * 4 + q;
        int e = EIJ[row];
        atomicAdd(psum + (size_t)e * 64 + col, acc3[mf][q]);
      }
  }
}

// ---------------- finalize: out = LN(edge_feat + psum/max(cnt,1) + b3) ----------------

__global__ __launch_bounds__(256) void k_final(
    const float* __restrict__ psum, const float* __restrict__ cnt,
    const float* __restrict__ ef, const float* __restrict__ b3,
    const float* __restrict__ gn, const float* __restrict__ bn,
    float* __restrict__ out) {
  int g = blockIdx.x * 256 + threadIdx.x;   // 4e6 threads, 4 lanes per edge
  int e = g >> 2, s = g & 3;
  float ic = 1.0f / fmaxf(cnt[e], 1.0f);
  float x[16];
  const float4* ps = (const float4*)(psum + (size_t)e * 64 + s * 16);
  const float4* fe = (const float4*)(ef + (size_t)e * 64 + s * 16);
  const float4* p3 = (const float4*)(b3 + s * 16);
#pragma unroll
  for (int i = 0; i < 4; ++i) {
    float4 a = ps[i], b = fe[i], c = p3[i];
    x[4 * i + 0] = b.x + a.x * ic + c.x;
    x[4 * i + 1] = b.y + a.y * ic + c.y;
    x[4 * i + 2] = b.z + a.z * ic + c.z;
    x[4 * i + 3] = b.w + a.w * ic + c.w;
  }
  float sum = 0.f, ss = 0.f;
#pragma unroll
  for (int i = 0; i < 16; ++i) { sum += x[i]; ss += x[i] * x[i]; }
  sum += __shfl_xor(sum, 1); ss += __shfl_xor(ss, 1);
  sum += __shfl_xor(sum, 2); ss += __shfl_xor(ss, 2);
  float mu = sum * (1.0f / 64.0f);
  float inv = rsqrtf(ss * (1.0f / 64.0f) - mu * mu + 1e-5f);
  float4* po = (float4*)(out + (size_t)e * 64 + s * 16);
#pragma unroll
  for (int i = 0; i < 4; ++i) {
    float4 gv = ((const float4*)(gn + s * 16))[i];
    float4 bv = ((const float4*)(bn + s * 16))[i];
    float4 o;
    o.x = (x[4 * i + 0] - mu) * inv * gv.x + bv.x;
    o.y = (x[4 * i + 1] - mu) * inv * gv.y + bv.y;
    o.z = (x[4 * i + 2] - mu) * inv * gv.z + bv.z;
    o.w = (x[4 * i + 3] - mu) * inv * gv.w + bv.w;
    po[i] = o;
  }
}

extern "C" void kernel_launch(void* const* d_in, const int* in_sizes, int n_in,
                              void* d_out, int out_size, void* d_ws, size_t ws_size,
                              hipStream_t stream) {
  const float* edge_feat = (const float*)d_in[0];
  const int* tidx = (const int*)d_in[1];
  const float* geo = (const float*)d_in[2];
  const float* W1 = (const float*)d_in[3];
  const float* b1 = (const float*)d_in[4];
  const float* g1 = (const float*)d_in[5];
  const float* be1 = (const float*)d_in[6];
  const float* W2 = (const float*)d_in[7];
  const float* b2 = (const float*)d_in[8];
  const float* g2 = (const float*)d_in[9];
  const float* be2 = (const float*)d_in[10];
  const float* W3 = (const float*)d_in[11];
  const float* b3 = (const float*)d_in[12];
  const float* gn = (const float*)d_in[13];
  const float* bn = (const float*)d_in[14];

  char* ws = (char*)d_ws;
  float* psum = (float*)(ws + OFF_PSUM);
  float* cnt = (float*)(ws + OFF_CNT);
  u16* ebf = (u16*)(ws + OFF_EBF);
  u16* wp1 = (u16*)(ws + OFF_WP1);
  u16* wp2 = (u16*)(ws + OFF_WP2);
  u16* wp3 = (u16*)(ws + OFF_WP3);
  float* out = (float*)d_out;

  hipMemsetAsync(ws, 0, 260000000ULL, stream);  // psum + cnt
  k_conv_edge<<<62500, 256, 0, stream>>>(edge_feat, ebf);
  k_pack_w<<<176, 256, 0, stream>>>(W1, W2, W3, wp1, wp2, wp3);

  hipFuncSetAttribute((const void*)k_triplet,
                      hipFuncAttributeMaxDynamicSharedMemorySize, LDS_TOTAL);
  k_triplet<<<15625, 512, LDS_TOTAL, stream>>>(ebf, tidx, geo, wp1, wp2, wp3,
                                               b1, g1, be1, b2, g2, be2, psum, cnt);
  k_final<<<15625, 256, 0, stream>>>(psum, cnt, edge_feat, b3, gn, bn, out);
}

// Round 2
// 1076.937 us; speedup vs baseline: 1.5000x; 1.5000x over previous
//
#include <hip/hip_runtime.h>
#include <hip/hip_bf16.h>
#include <stdint.h>

typedef __attribute__((ext_vector_type(8))) short short8;
typedef __attribute__((ext_vector_type(4))) float f32x4;
typedef unsigned short u16;

// ---------------- workspace layout (bytes) ----------------
#define OFF_PSUM 0ULL                      // 1e6 * 64 * 4 = 256,000,000
#define OFF_CNT  256000000ULL              // 1e6 * 4
#define OFF_EBF  260000000ULL              // 1e6 * 64 * 2 = 128,000,000
#define OFF_WP1  388000000ULL              // 20*128*8*2 = 40960
#define OFF_WP2  (OFF_WP1 + 40960ULL)      // 16*128*8*2 = 32768
#define OFF_WP3  (OFF_WP2 + 32768ULL)      // 16*64*8*2  = 16384
#define OFF_S2   (OFF_WP3 + 16384ULL)      // 128*4
#define OFF_C2   (OFF_S2 + 512ULL)         // 128*4
#define OFF_S3   (OFF_C2 + 512ULL)         // 64*4
#define OFF_T3   (OFF_S3 + 256ULL)         // 64*4

// ---------------- LDS layout for k_triplet (bytes) ----------------
// X: [128][320] bf16 (swizzled for k<128, plain 256..319), aliased later by
// H/M: [128][256] bf16 swizzled (byte ^= (row&7)<<4)
#define LDS_P1S 40960   // float[128][4] row-sum partials, layer1
#define LDS_P1Q 43008   // float[128][4] row-sumsq partials, layer1
#define LDS_P2S 45056
#define LDS_P2Q 47104
#define LDS_EIJ 49152   // int[128]
#define LDS_EKJ 49664   // int[128]
#define LDS_TOTAL 50176

__device__ __forceinline__ u16 f2bf(float f) {
  union { float f; uint32_t u; } c; c.f = f;
  uint32_t u = c.u;
  return (u16)((u + 0x7FFFu + ((u >> 16) & 1u)) >> 16);  // RNE
}
__device__ __forceinline__ float silu(float y) {
  return y / (1.0f + __expf(-y));
}

#define MFMA16(a, b, c) __builtin_amdgcn_mfma_f32_16x16x32_bf16((a), (b), (c), 0, 0, 0)

// ---------------- prep kernels ----------------

__global__ __launch_bounds__(256) void k_conv_edge(const float* __restrict__ ef,
                                                   u16* __restrict__ ebf) {
  int i = blockIdx.x * 256 + threadIdx.x;  // < 16,000,000
  float4 v = ((const float4*)ef)[i];
  ushort4 o;
  o.x = f2bf(v.x); o.y = f2bf(v.y); o.z = f2bf(v.z); o.w = f2bf(v.w);
  ((ushort4*)ebf)[i] = o;
}

// pack weights bf16 into B-fragment order: wp[(k>>3)*N + n][k&7]
// W2 pre-scaled by g1[k], W3 pre-scaled by g2[k] (LN folded into GEMM).
__global__ __launch_bounds__(256) void k_pack_w(const float* __restrict__ W1,
                                                const float* __restrict__ W2,
                                                const float* __restrict__ W3,
                                                const float* __restrict__ g1,
                                                const float* __restrict__ g2,
                                                u16* __restrict__ wp1,
                                                u16* __restrict__ wp2,
                                                u16* __restrict__ wp3) {
  int i = blockIdx.x * 256 + threadIdx.x;  // < 45056
  if (i < 20480) {                         // W1: K padded 132->160, N=128
    int j = i & 7, n = (i >> 3) & 127, kb = i >> 10;
    int k = kb * 8 + j;
    wp1[i] = (k < 132) ? f2bf(W1[k * 128 + n]) : (u16)0;
  } else if (i < 36864) {                  // W2': K=128, N=128
    int i2 = i - 20480;
    int j = i2 & 7, n = (i2 >> 3) & 127, kb = i2 >> 10;
    int k = kb * 8 + j;
    wp2[i2] = f2bf(g1[k] * W2[k * 128 + n]);
  } else if (i < 45056) {                  // W3': K=128, N=64
    int i3 = i - 36864;
    int j = i3 & 7, n = (i3 >> 3) & 63, kb = i3 >> 9;
    int k = kb * 8 + j;
    wp3[i3] = f2bf(g2[k] * W3[k * 64 + n]);
  }
}

// LN-fold constant vectors: s2[n]=sum_k g1[k]W2[k,n], c2[n]=sum_k be1[k]W2[k,n]+b2[n]
//                           s3[n]=sum_k g2[k]W3[k,n], t3[n]=sum_k be2[k]W3[k,n]
__global__ __launch_bounds__(256) void k_pack_vec(
    const float* __restrict__ W2, const float* __restrict__ W3,
    const float* __restrict__ g1, const float* __restrict__ be1, const float* __restrict__ b2,
    const float* __restrict__ g2, const float* __restrict__ be2,
    float* __restrict__ s2, float* __restrict__ c2,
    float* __restrict__ s3, float* __restrict__ t3) {
  int t = threadIdx.x;
  if (t < 128) {
    float a = 0.f, b = 0.f;
    for (int k = 0; k < 128; ++k) {
      float w = W2[k * 128 + t];
      a += g1[k] * w; b += be1[k] * w;
    }
    s2[t] = a; c2[t] = b + b2[t];
  } else if (t < 192) {
    int n = t - 128;
    float a = 0.f, b = 0.f;
    for (int k = 0; k < 128; ++k) {
      float w = W3[k * 64 + n];
      a += g2[k] * w; b += be2[k] * w;
    }
    s3[n] = a; t3[n] = b;
  }
}

// ---------------- main triplet kernel ----------------
// tile = 128 triplets, 512 threads = 8 waves as 2(M) x 4(N); per-wave C = 64x32.
// B fragments read directly from global packed weights (L1/L2-resident).

__global__ __launch_bounds__(512, 4) void k_triplet(
    const u16* __restrict__ ebf, const int* __restrict__ tidx,
    const float* __restrict__ geo,
    const u16* __restrict__ wp1, const u16* __restrict__ wp2, const u16* __restrict__ wp3,
    const float* __restrict__ b1,
    const float* __restrict__ s2v, const float* __restrict__ c2v,
    const float* __restrict__ s3v,
    float* __restrict__ psum, float* __restrict__ cnt) {
  extern __shared__ char smem[];
  float* P1S = (float*)(smem + LDS_P1S);
  float* P1Q = (float*)(smem + LDS_P1Q);
  float* P2S = (float*)(smem + LDS_P2S);
  float* P2Q = (float*)(smem + LDS_P2Q);
  int* EIJ = (int*)(smem + LDS_EIJ);
  int* EKJ = (int*)(smem + LDS_EKJ);

  const int tid = threadIdx.x;
  const int wave = tid >> 6, lane = tid & 63;
  const int wm = wave >> 2, wn = wave & 3;
  const int l15 = lane & 15, lg = lane >> 4;
  const int t0 = blockIdx.x * 128;
  const int n0 = wn * 32 + l15;        // GEMM1/2 col pair base
  const int n3 = wn * 16 + l15;        // GEMM3 col
  const int rowA = wm * 64 + l15;      // A-frag row base

  // prefetch GEMM1 B fragments + bias (global, L1-cached)
  const short8* wb1 = (const short8*)wp1;
  short8 w1f[10];
#pragma unroll
  for (int s5 = 0; s5 < 5; ++s5) {
    int kb = s5 * 4 + lg;
    w1f[2 * s5] = wb1[kb * 128 + n0];
    w1f[2 * s5 + 1] = wb1[kb * 128 + n0 + 16];
  }
  float b1c0 = b1[n0], b1c1 = b1[n0 + 16];

  if (tid < 128) {
    int2 p = ((const int2*)tidx)[t0 + tid];
    EIJ[tid] = p.x; EKJ[tid] = p.y;
    atomicAdd(&cnt[p.x], 1.0f);
  }
  __syncthreads();

  // stage X = [f_ij | f_kj | geo | 0] as [128][320B], swizzled in first 256B
  {
    const int r = tid >> 2, s = tid & 3;
    const int e = (s < 2) ? EIJ[r] : EKJ[r];
    const uint4* src = (const uint4*)(ebf + (size_t)e * 64) + (s & 1) * 4;
    uint4 v0 = src[0], v1 = src[1], v2 = src[2], v3 = src[3];
    const int swz = (r & 7) << 4;
    char* rowp = smem + r * 320;
    *(uint4*)(rowp + ((s * 64 + 0) ^ swz)) = v0;
    *(uint4*)(rowp + ((s * 64 + 16) ^ swz)) = v1;
    *(uint4*)(rowp + ((s * 64 + 32) ^ swz)) = v2;
    *(uint4*)(rowp + ((s * 64 + 48) ^ swz)) = v3;
    if (s == 0) {
      float4 gq = ((const float4*)geo)[t0 + r];
      ushort4 gb;
      gb.x = f2bf(gq.x); gb.y = f2bf(gq.y); gb.z = f2bf(gq.z); gb.w = f2bf(gq.w);
      *(ushort4*)(rowp + 256) = gb;
      *(uint2*)(rowp + 264) = (uint2){0, 0};
    } else {
      *(uint4*)(rowp + 256 + s * 16) = (uint4){0, 0, 0, 0};
    }
  }
  __syncthreads();

  // ---- GEMM1: X @ W1  (K=160) ----
  f32x4 acc[4][2];
#pragma unroll
  for (int mf = 0; mf < 4; ++mf) { acc[mf][0] = (f32x4)0.f; acc[mf][1] = (f32x4)0.f; }
#pragma unroll
  for (int s5 = 0; s5 < 5; ++s5) {
    short8 a[4];
#pragma unroll
    for (int mf = 0; mf < 4; ++mf) {
      int row = rowA + mf * 16;
      int off = s5 * 64 + lg * 16;
      if (s5 < 4) off ^= (row & 7) << 4;
      a[mf] = *(const short8*)(smem + row * 320 + off);
    }
#pragma unroll
    for (int mf = 0; mf < 4; ++mf) {
      acc[mf][0] = MFMA16(a[mf], w1f[2 * s5], acc[mf][0]);
      acc[mf][1] = MFMA16(a[mf], w1f[2 * s5 + 1], acc[mf][1]);
    }
  }

  // layer-1 epilogue: silu in-reg, row-stat partials via shfl, raw H kept
#pragma unroll
  for (int mf = 0; mf < 4; ++mf)
#pragma unroll
    for (int q = 0; q < 4; ++q) {
      float v0 = silu(acc[mf][0][q] + b1c0);
      float v1 = silu(acc[mf][1][q] + b1c1);
      acc[mf][0][q] = v0; acc[mf][1][q] = v1;
      float ps = v0 + v1, pq = v0 * v0 + v1 * v1;
      ps += __shfl_xor(ps, 1); pq += __shfl_xor(pq, 1);
      ps += __shfl_xor(ps, 2); pq += __shfl_xor(pq, 2);
      ps += __shfl_xor(ps, 4); pq += __shfl_xor(pq, 4);
      ps += __shfl_xor(ps, 8); pq += __shfl_xor(pq, 8);
      if (l15 == 0) {
        int row = wm * 64 + mf * 16 + lg * 4 + q;
        P1S[row * 4 + wn] = ps; P1Q[row * 4 + wn] = pq;
      }
    }
  __syncthreads();  // A1: all X reads + P1 writes done

  // prefetch GEMM2 B frags + fold constants (overlap with H writes)
  const short8* wb2 = (const short8*)wp2;
  short8 w2f[8];
#pragma unroll
  for (int s4 = 0; s4 < 4; ++s4) {
    int kb = s4 * 4 + lg;
    w2f[2 * s4] = wb2[kb * 128 + n0];
    w2f[2 * s4 + 1] = wb2[kb * 128 + n0 + 16];
  }
  float s2c0 = s2v[n0], s2c1 = s2v[n0 + 16];
  float c2c0 = c2v[n0], c2c1 = c2v[n0 + 16];

  // write raw H (bf16) into swizzled [128][256B]
#pragma unroll
  for (int mf = 0; mf < 4; ++mf)
#pragma unroll
    for (int f = 0; f < 2; ++f)
#pragma unroll
      for (int q = 0; q < 4; ++q) {
        int row = wm * 64 + mf * 16 + lg * 4 + q;
        int cb = (wn * 32 + f * 16 + l15) << 1;
        *(u16*)(smem + row * 256 + (cb ^ ((row & 7) << 4))) = f2bf(acc[mf][f][q]);
      }
  __syncthreads();  // A2: H visible

  // ---- GEMM2: H @ W2'  (K=128) ----
#pragma unroll
  for (int mf = 0; mf < 4; ++mf) { acc[mf][0] = (f32x4)0.f; acc[mf][1] = (f32x4)0.f; }
#pragma unroll
  for (int s4 = 0; s4 < 4; ++s4) {
    short8 a[4];
#pragma unroll
    for (int mf = 0; mf < 4; ++mf) {
      int row = rowA + mf * 16;
      a[mf] = *(const short8*)(smem + row * 256 + ((s4 * 64 + lg * 16) ^ ((row & 7) << 4)));
    }
#pragma unroll
    for (int mf = 0; mf < 4; ++mf) {
      acc[mf][0] = MFMA16(a[mf], w2f[2 * s4], acc[mf][0]);
      acc[mf][1] = MFMA16(a[mf], w2f[2 * s4 + 1], acc[mf][1]);
    }
  }

  // layer-2 epilogue: apply folded LN1, silu, layer-2 partials
#pragma unroll
  for (int mf = 0; mf < 4; ++mf)
#pragma unroll
    for (int q = 0; q < 4; ++q) {
      int row = wm * 64 + mf * 16 + lg * 4 + q;
      float4 sv = *(const float4*)&P1S[row * 4];
      float4 qv = *(const float4*)&P1Q[row * 4];
      float sum = sv.x + sv.y + sv.z + sv.w;
      float sq = qv.x + qv.y + qv.z + qv.w;
      float mu = sum * 0.0078125f;
      float inv = rsqrtf(fmaxf(sq * 0.0078125f - mu * mu, 0.f) + 1e-5f);
      float f0 = inv * (acc[mf][0][q] - mu * s2c0) + c2c0;
      float f1 = inv * (acc[mf][1][q] - mu * s2c1) + c2c1;
      float v0 = silu(f0), v1 = silu(f1);
      acc[mf][0][q] = v0; acc[mf][1][q] = v1;
      float ps = v0 + v1, pq = v0 * v0 + v1 * v1;
      ps += __shfl_xor(ps, 1); pq += __shfl_xor(pq, 1);
      ps += __shfl_xor(ps, 2); pq += __shfl_xor(pq, 2);
      ps += __shfl_xor(ps, 4); pq += __shfl_xor(pq, 4);
      ps += __shfl_xor(ps, 8); pq += __shfl_xor(pq, 8);
      if (l15 == 0) { P2S[row * 4 + wn] = ps; P2Q[row * 4 + wn] = pq; }
    }

  // prefetch GEMM3 B frags + s3
  const short8* wb3 = (const short8*)wp3;
  short8 w3f[4];
#pragma unroll
  for (int s4 = 0; s4 < 4; ++s4) w3f[s4] = wb3[(s4 * 4 + lg) * 64 + n3];
  float s3c = s3v[n3];

  __syncthreads();  // B: all H + P1 reads done, P2 written

  // write raw M (bf16)
#pragma unroll
  for (int mf = 0; mf < 4; ++mf)
#pragma unroll
    for (int f = 0; f < 2; ++f)
#pragma unroll
      for (int q = 0; q < 4; ++q) {
        int row = wm * 64 + mf * 16 + lg * 4 + q;
        int cb = (wn * 32 + f * 16 + l15) << 1;
        *(u16*)(smem + row * 256 + (cb ^ ((row & 7) << 4))) = f2bf(acc[mf][f][q]);
      }
  __syncthreads();  // C: M visible

  // ---- GEMM3: M @ W3'  (K=128, N=64) + folded LN2 + atomic scatter ----
  f32x4 acc3[4];
#pragma unroll
  for (int mf = 0; mf < 4; ++mf) acc3[mf] = (f32x4)0.f;
#pragma unroll
  for (int s4 = 0; s4 < 4; ++s4) {
    short8 a[4];
#pragma unroll
    for (int mf = 0; mf < 4; ++mf) {
      int row = rowA + mf * 16;
      a[mf] = *(const short8*)(smem + row * 256 + ((s4 * 64 + lg * 16) ^ ((row & 7) << 4)));
    }
#pragma unroll
    for (int mf = 0; mf < 4; ++mf) acc3[mf] = MFMA16(a[mf], w3f[s4], acc3[mf]);
  }
#pragma unroll
  for (int mf = 0; mf < 4; ++mf)
#pragma unroll
    for (int q = 0; q < 4; ++q) {
      int row = wm * 64 + mf * 16 + lg * 4 + q;
      float4 sv = *(const float4*)&P2S[row * 4];
      float4 qv = *(const float4*)&P2Q[row * 4];
      float sum = sv.x + sv.y + sv.z + sv.w;
      float sq = qv.x + qv.y + qv.z + qv.w;
      float mu = sum * 0.0078125f;
      float inv = rsqrtf(fmaxf(sq * 0.0078125f - mu * mu, 0.f) + 1e-5f);
      float y = inv * (acc3[mf][q] - mu * s3c);
      int e = EIJ[row];
      atomicAdd(psum + (size_t)e * 64 + n3, y);
    }
}

// ---------------- finalize ----------------
// out = LN(ef + psum/max(cnt,1) + b3 + (cnt>0 ? t3 : 0), gn, bn)

__global__ __launch_bounds__(256) void k_final(
    const float* __restrict__ psum, const float* __restrict__ cnt,
    const float* __restrict__ ef, const float* __restrict__ b3,
    const float* __restrict__ t3, const float* __restrict__ gn,
    const float* __restrict__ bn, float* __restrict__ out) {
  int g = blockIdx.x * 256 + threadIdx.x;  // 4e6 threads, 4 lanes/edge
  int e = g >> 2, s = g & 3;
  float cv = cnt[e];
  float ic = 1.0f / fmaxf(cv, 1.0f);
  float tw = (cv > 0.f) ? 1.0f : 0.0f;
  float x[16];
  const float4* ps = (const float4*)(psum + (size_t)e * 64 + s * 16);
  const float4* fe = (const float4*)(ef + (size_t)e * 64 + s * 16);
  const float4* p3 = (const float4*)(b3 + s * 16);
  const float4* pt = (const float4*)(t3 + s * 16);
#pragma unroll
  for (int i = 0; i < 4; ++i) {
    float4 a = ps[i], b = fe[i], c = p3[i], d = pt[i];
    x[4 * i + 0] = b.x + a.x * ic + c.x + tw * d.x;
    x[4 * i + 1] = b.y + a.y * ic + c.y + tw * d.y;
    x[4 * i + 2] = b.z + a.z * ic + c.z + tw * d.z;
    x[4 * i + 3] = b.w + a.w * ic + c.w + tw * d.w;
  }
  float sum = 0.f, ss = 0.f;
#pragma unroll
  for (int i = 0; i < 16; ++i) { sum += x[i]; ss += x[i] * x[i]; }
  sum += __shfl_xor(sum, 1); ss += __shfl_xor(ss, 1);
  sum += __shfl_xor(sum, 2); ss += __shfl_xor(ss, 2);
  float mu = sum * (1.0f / 64.0f);
  float inv = rsqrtf(ss * (1.0f / 64.0f) - mu * mu + 1e-5f);
  float4* po = (float4*)(out + (size_t)e * 64 + s * 16);
#pragma unroll
  for (int i = 0; i < 4; ++i) {
    float4 gv = ((const float4*)(gn + s * 16))[i];
    float4 bv = ((const float4*)(bn + s * 16))[i];
    float4 o;
    o.x = (x[4 * i + 0] - mu) * inv * gv.x + bv.x;
    o.y = (x[4 * i + 1] - mu) * inv * gv.y + bv.y;
    o.z = (x[4 * i + 2] - mu) * inv * gv.z + bv.z;
    o.w = (x[4 * i + 3] - mu) * inv * gv.w + bv.w;
    po[i] = o;
  }
}

extern "C" void kernel_launch(void* const* d_in, const int* in_sizes, int n_in,
                              void* d_out, int out_size, void* d_ws, size_t ws_size,
                              hipStream_t stream) {
  const float* edge_feat = (const float*)d_in[0];
  const int* tidx = (const int*)d_in[1];
  const float* geo = (const float*)d_in[2];
  const float* W1 = (const float*)d_in[3];
  const float* b1 = (const float*)d_in[4];
  const float* g1 = (const float*)d_in[5];
  const float* be1 = (const float*)d_in[6];
  const float* W2 = (const float*)d_in[7];
  const float* b2 = (const float*)d_in[8];
  const float* g2 = (const float*)d_in[9];
  const float* be2 = (const float*)d_in[10];
  const float* W3 = (const float*)d_in[11];
  const float* b3 = (const float*)d_in[12];
  const float* gn = (const float*)d_in[13];
  const float* bn = (const float*)d_in[14];

  char* ws = (char*)d_ws;
  float* psum = (float*)(ws + OFF_PSUM);
  float* cnt = (float*)(ws + OFF_CNT);
  u16* ebf = (u16*)(ws + OFF_EBF);
  u16* wp1 = (u16*)(ws + OFF_WP1);
  u16* wp2 = (u16*)(ws + OFF_WP2);
  u16* wp3 = (u16*)(ws + OFF_WP3);
  float* s2 = (float*)(ws + OFF_S2);
  float* c2 = (float*)(ws + OFF_C2);
  float* s3 = (float*)(ws + OFF_S3);
  float* t3 = (float*)(ws + OFF_T3);
  float* out = (float*)d_out;

  hipMemsetAsync(ws, 0, 260000000ULL, stream);  // psum + cnt
  k_conv_edge<<<62500, 256, 0, stream>>>(edge_feat, ebf);
  k_pack_w<<<176, 256, 0, stream>>>(W1, W2, W3, g1, g2, wp1, wp2, wp3);
  k_pack_vec<<<1, 256, 0, stream>>>(W2, W3, g1, be1, b2, g2, be2, s2, c2, s3, t3);

  k_triplet<<<15625, 512, LDS_TOTAL, stream>>>(ebf, tidx, geo, wp1, wp2, wp3,
                                               b1, s2, c2, s3, psum, cnt);
  k_final<<<15625, 256, 0, stream>>>(psum, cnt, edge_feat, b3, t3, gn, bn, out);
}